// Round 5
// baseline (79.531 us; speedup 1.0000x reference)
//
#include <hip/hip_runtime.h>
#include <math.h>

#define BB 8
#define NN 256
#define F_IN 64
#define HID 128
constexpr float NEG_SLOPE = 0.2f;
#define BN (BB * NN)
// ws layout: sd[0..BN) = s, sd[BN..2BN) = d, sd[2BN] = coef

// ---------------------------------------------------------------------------
// Kernel A: 8 nodes per 256-thread block (grid 257). W_lin staged transposed
// (WT[f][h], stride 129: both the scatter writes and the compute reads spread
// all 32 banks 2-way = free). 8 src rows staged transposed (sT[f][n]); inner
// loop per f: 1 b32 WT read + 1 uniform-broadcast b128 sT read + 4 FMA.
// Block 256 computes coef = W_edge . a_edge.
// ---------------------------------------------------------------------------
__global__ void __launch_bounds__(256) attn_sd_kernel(
    const float* __restrict__ src, const float* __restrict__ W_lin,
    const float* __restrict__ a_src, const float* __restrict__ a_dst,
    const float* __restrict__ W_edge, const float* __restrict__ a_edge,
    float* __restrict__ sd)
{
    const int blk = blockIdx.x;
    const int t = threadIdx.x;

    if (blk == BN / 8) {
        if (t < 64) {
            float v = W_edge[t] * a_edge[t];
            #pragma unroll
            for (int off = 32; off > 0; off >>= 1) v += __shfl_xor(v, off);
            if (t == 0) sd[2 * BN] = v;
        }
        return;
    }

    __shared__ float WT[F_IN][129];   // WT[f][h] = W_lin[h][f]
    __shared__ float sT[F_IN][8];     // sT[f][n] = src[nb+n][f]
    __shared__ float red[4][8];       // per-wave partials: 4 nodes x {s,d}

    #pragma unroll
    for (int k = 0; k < 8; ++k) {
        int idx4 = t + k * 256;            // [0, 2048)
        int h = idx4 >> 4;
        int f4 = idx4 & 15;
        float4 w = reinterpret_cast<const float4*>(W_lin)[idx4];
        WT[4 * f4 + 0][h] = w.x;
        WT[4 * f4 + 1][h] = w.y;
        WT[4 * f4 + 2][h] = w.z;
        WT[4 * f4 + 3][h] = w.w;
    }
    const int nb = blk * 8;
    #pragma unroll
    for (int k = 0; k < 2; ++k) {
        int idx = t + k * 256;
        int n = idx >> 6, f = idx & 63;
        sT[f][n] = src[(nb + n) * F_IN + f];
    }
    __syncthreads();

    const int h = t & 127;
    const int g = t >> 7;
    float acc0 = 0.f, acc1 = 0.f, acc2 = 0.f, acc3 = 0.f;
    #pragma unroll
    for (int f = 0; f < F_IN; ++f) {
        float w = WT[f][h];
        float4 s = *reinterpret_cast<const float4*>(&sT[f][g * 4]);
        acc0 = fmaf(w, s.x, acc0);
        acc1 = fmaf(w, s.y, acc1);
        acc2 = fmaf(w, s.z, acc2);
        acc3 = fmaf(w, s.w, acc3);
    }
    const float as = a_src[h], ad = a_dst[h];
    float v[8];
    {
        float x0 = acc0 > 0.f ? acc0 : NEG_SLOPE * acc0;
        float x1 = acc1 > 0.f ? acc1 : NEG_SLOPE * acc1;
        float x2 = acc2 > 0.f ? acc2 : NEG_SLOPE * acc2;
        float x3 = acc3 > 0.f ? acc3 : NEG_SLOPE * acc3;
        v[0] = x0 * as; v[1] = x1 * as; v[2] = x2 * as; v[3] = x3 * as;
        v[4] = x0 * ad; v[5] = x1 * ad; v[6] = x2 * ad; v[7] = x3 * ad;
    }
    #pragma unroll
    for (int off = 32; off > 0; off >>= 1) {
        #pragma unroll
        for (int q = 0; q < 8; ++q) v[q] += __shfl_xor(v[q], off);
    }
    const int wave = t >> 6, lane = t & 63;
    if (lane == 0) {
        #pragma unroll
        for (int q = 0; q < 8; ++q) red[wave][q] = v[q];
    }
    __syncthreads();
    if (t == 0) {
        #pragma unroll
        for (int n = 0; n < 4; ++n) {
            sd[nb + n]      = red[0][n]     + red[1][n];
            sd[BN + nb + n] = red[0][4 + n] + red[1][4 + n];
        }
    }
    if (t == 128) {
        #pragma unroll
        for (int n = 0; n < 4; ++n) {
            sd[nb + 4 + n]      = red[2][n]     + red[3][n];
            sd[BN + nb + 4 + n] = red[2][4 + n] + red[3][4 + n];
        }
    }
}

// ---------------------------------------------------------------------------
// Kernel B: 4 rows per 256-thread block (grid 512). Panel staged row-major
// with stride 68 (68 = 4 mod 32, 16B-aligned): staging = 16 ds_write_b128
// with even 8-access/bank spread (minimal for b128), own-row read = 16
// ds_read_b128 (same even spread), row-i reads uniform broadcast.
// All 4 rows batched: one 4-wide butterfly max, ONE barrier, one 4-wide
// butterfly sum, ONE barrier (was 12 barriers).
// ---------------------------------------------------------------------------
__global__ void __launch_bounds__(256) attn_row_kernel(
    const float* __restrict__ src, const int* __restrict__ adj,
    const int* __restrict__ mask, const float* __restrict__ sd,
    float* __restrict__ out)
{
    const int blk = blockIdx.x;            // rows 4*blk .. 4*blk+3
    const int j = threadIdx.x;
    const int b = blk >> 6;                // 64 blocks per batch

    __shared__ float pT[NN][68];           // 69.6 KB -> 2 blocks/CU
    __shared__ float redm[4][4], reds[4][4];

    const float4* srcb4 = reinterpret_cast<const float4*>(src + b * NN * F_IN);
    #pragma unroll
    for (int k = 0; k < 16; ++k) {
        int idx4 = j + k * 256;            // [0, 4096)
        int n = idx4 >> 4;
        int f4 = idx4 & 15;
        float4 v = srcb4[idx4];
        *reinterpret_cast<float4*>(&pT[n][4 * f4]) = v;
    }
    __syncthreads();

    // own row j in registers: 16 ds_read_b128, even bank spread
    float4 pj[16];
    #pragma unroll
    for (int f4 = 0; f4 < 16; ++f4)
        pj[f4] = *reinterpret_cast<const float4*>(&pT[j][4 * f4]);

    const float dj   = sd[BN + b * NN + j];
    const float coef = sd[2 * BN];
    const int base = blk * 4;
    const int wave = j >> 6, lane = j & 63;

    // --- compute a-values for all 4 rows ---
    float aa[4];
    #pragma unroll
    for (int r = 0; r < 4; ++r) {
        const int grow = base + r;         // b*NN + i
        const int il = grow & (NN - 1);
        float sq = 0.0f;
        #pragma unroll
        for (int f4 = 0; f4 < 16; ++f4) {
            float4 pi = *reinterpret_cast<const float4*>(&pT[il][4 * f4]); // bcast
            float d0 = pi.x - pj[f4].x;
            float d1 = pi.y - pj[f4].y;
            float d2 = pi.z - pj[f4].z;
            float d3 = pi.w - pj[f4].w;
            sq = fmaf(d0, d0, sq); sq = fmaf(d1, d1, sq);
            sq = fmaf(d2, d2, sq); sq = fmaf(d3, d3, sq);
        }
        const float nrm = sq > 0.0f ? sqrtf(sq) : 0.0f;
        const float e = sd[grow] + dj + nrm * coef * (float)adj[grow * NN + j];
        aa[r] = e * (float)mask[grow * NN + j];
    }

    // --- 4-wide butterfly max (ILP across rows), one barrier ---
    float m[4] = {aa[0], aa[1], aa[2], aa[3]};
    #pragma unroll
    for (int off = 32; off > 0; off >>= 1) {
        #pragma unroll
        for (int r = 0; r < 4; ++r) m[r] = fmaxf(m[r], __shfl_xor(m[r], off));
    }
    if (lane == 0) {
        #pragma unroll
        for (int r = 0; r < 4; ++r) redm[wave][r] = m[r];
    }
    __syncthreads();

    float ex[4], ss[4];
    #pragma unroll
    for (int r = 0; r < 4; ++r) {
        const float rowmax = fmaxf(fmaxf(redm[0][r], redm[1][r]),
                                   fmaxf(redm[2][r], redm[3][r]));
        ex[r] = __expf(aa[r] - rowmax);
        ss[r] = ex[r];
    }
    #pragma unroll
    for (int off = 32; off > 0; off >>= 1) {
        #pragma unroll
        for (int r = 0; r < 4; ++r) ss[r] += __shfl_xor(ss[r], off);
    }
    if (lane == 0) {
        #pragma unroll
        for (int r = 0; r < 4; ++r) reds[wave][r] = ss[r];
    }
    __syncthreads();

    #pragma unroll
    for (int r = 0; r < 4; ++r) {
        const float inv = 1.0f / (reds[0][r] + reds[1][r] +
                                  reds[2][r] + reds[3][r]);
        out[(base + r) * NN + j] = ex[r] * inv;   // coalesced
    }
}

extern "C" void kernel_launch(void* const* d_in, const int* in_sizes, int n_in,
                              void* d_out, int out_size, void* d_ws, size_t ws_size,
                              hipStream_t stream) {
    const float* src    = (const float*)d_in[0];
    const int*   adj    = (const int*)  d_in[1];
    const int*   mask   = (const int*)  d_in[2];
    const float* W_lin  = (const float*)d_in[3];
    const float* a_src  = (const float*)d_in[4];
    const float* a_dst  = (const float*)d_in[5];
    const float* W_edge = (const float*)d_in[6];
    const float* a_edge = (const float*)d_in[7];
    float* out = (float*)d_out;
    float* sd  = (float*)d_ws;   // 2*BN + 1 floats

    attn_sd_kernel<<<BN / 8 + 1, 256, 0, stream>>>(src, W_lin, a_src, a_dst,
                                                   W_edge, a_edge, sd);
    attn_row_kernel<<<BN / 4, 256, 0, stream>>>(src, adj, mask, sd, out);
}